// Round 3
// baseline (392.032 us; speedup 1.0000x reference)
//
#include <hip/hip_runtime.h>

// Soft-DTW, B=64, L=1024, C=64, gamma=1.
// 8 row-bands of 128 rows per batch; wave = band; lane r handles TWO rows:
// sub-band A row r (col s-r) and sub-band B row 64+r (col s-r-64), one skewed
// sweep of s = 0..1150 in 18 64-step chunks. A->B handoff inside the wave via
// DPP wave_ror:1 (lane63's A value -> lane0's B up), zero LDS in the chain.
// 4 waves/block, 2 blocks/batch (128 blocks, 1/CU). Band handoff: LDS Hb +
// flags in-block; one global HX + agent flag per batch across blocks.
// DP in base-2 domain (D pre-scaled by 1/ln2, v_exp/v_log native, out * ln2).

typedef unsigned short ushort_t;
typedef __attribute__((ext_vector_type(8))) short short8;
typedef __attribute__((ext_vector_type(4))) float f32x4;
typedef __attribute__((ext_vector_type(4))) unsigned short ushort4v;

constexpr int B_ = 64, L_ = 1024, C_ = 64;
constexpr int DSTR = 130;   // u16 row stride (65 dwords): (lane+c)%32 banks, 2-way free

#define BIGV 1e10f
#define INV_LN2 1.44269504088896340736f
#define LN2F 0.69314718055994530942f

static __device__ __forceinline__ ushort_t f2bf(float f) {
  unsigned u = __builtin_bit_cast(unsigned, f);
  unsigned r = (u + 0x7fffu + ((u >> 16) & 1u)) >> 16;
  return (ushort_t)r;
}
static __device__ __forceinline__ unsigned cvt_pk_bf16(float lo, float hi) {
  unsigned r; asm("v_cvt_pk_bf16_f32 %0, %1, %2" : "=v"(r) : "v"(lo), "v"(hi)); return r;
}
// lane i <- lane i-1; lane 0 <- old[0]   (wave_shr:1)
static __device__ __forceinline__ float dpp_shr1(float old, float src) {
  return __builtin_bit_cast(float, __builtin_amdgcn_update_dpp(
      __builtin_bit_cast(int, old), __builtin_bit_cast(int, src), 0x138, 0xF, 0xF, false));
}
// rotate: lane i <- lane i+1 toward 0? NO: lane i <- lane i+1 (shl, lane63 keeps old)
static __device__ __forceinline__ float dpp_shl1(float v) {
  return __builtin_bit_cast(float, __builtin_amdgcn_update_dpp(
      __builtin_bit_cast(int, v), __builtin_bit_cast(int, v), 0x130, 0xF, 0xF, false));
}
// rotate right: lane i <- lane i-1, lane 0 <- lane 63   (wave_ror:1)
static __device__ __forceinline__ float dpp_ror1(float v) {
  return __builtin_bit_cast(float, __builtin_amdgcn_update_dpp(
      __builtin_bit_cast(int, v), __builtin_bit_cast(int, v), 0x13C, 0xF, 0xF, false));
}

// Pass 1: bf16 conversion (RNE), squared norms pre-scaled by 1/ln2, zero flags.
__global__ __launch_bounds__(256) void prep_kernel(
    const float* __restrict__ x, const float* __restrict__ y,
    ushort_t* __restrict__ xb, ushort_t* __restrict__ yb,
    float* __restrict__ x2, float* __restrict__ y2, int* __restrict__ flagsG)
{
  if (blockIdx.x == 0 && threadIdx.x < 64) flagsG[threadIdx.x] = 0;
  const int lane = threadIdx.x & 63;
  const int sub = lane >> 4;
  const int cg  = lane & 15;
  const int wv = (blockIdx.x * blockDim.x + threadIdx.x) >> 6;
  const int nw = (gridDim.x * blockDim.x) >> 6;
  const int totalGroups = (2 * B_ * L_) >> 2;
  for (int g = wv; g < totalGroups; g += nw) {
    int r = g * 4 + sub;
    const float* src; ushort_t* dst; float* nrm;
    if (r < B_ * L_) { src = x; dst = xb; nrm = x2; }
    else             { r -= B_ * L_; src = y; dst = yb; nrm = y2; }
    const float4 v = *(const float4*)(src + (size_t)r * C_ + cg * 4);
    ushort4v p;
    p.x = f2bf(v.x); p.y = f2bf(v.y); p.z = f2bf(v.z); p.w = f2bf(v.w);
    *(ushort4v*)(dst + (size_t)r * C_ + cg * 4) = p;
    float s = v.x*v.x + v.y*v.y + v.z*v.z + v.w*v.w;
    s += __shfl_xor(s, 1); s += __shfl_xor(s, 2);
    s += __shfl_xor(s, 4); s += __shfl_xor(s, 8);
    if (cg == 0) nrm[r] = s * INV_LN2;
  }
}

// Gram 64x64 tile -> skewed LDS rows [rowBase..rowBase+63], slot = (col + localRow) & 127.
template<int MTB>
static __device__ __forceinline__ void gram_tile(
    const short8 (&af)[8][2], const f32x4 (&x2q)[8],
    const short8 (&b0)[4], const short8 (&b1)[4], const f32x4 y2r,
    ushort_t* __restrict__ Dtw, const int rowBase, const int cb,
    const int m, const int q)
{
  #pragma unroll
  for (int mt = 0; mt < 4; ++mt) {
    const int r0 = mt * 16 + q * 4;
    #pragma unroll
    for (int nt = 0; nt < 4; ++nt) {
      f32x4 acc = {0.f, 0.f, 0.f, 0.f};
      acc = __builtin_amdgcn_mfma_f32_16x16x32_bf16(af[MTB + mt][0], b0[nt], acc, 0, 0, 0);
      acc = __builtin_amdgcn_mfma_f32_16x16x32_bf16(af[MTB + mt][1], b1[nt], acc, 0, 0, 0);
      const float y2v = y2r[nt];
      float d0 = fmaf(acc[0], -2.f * INV_LN2, x2q[MTB + mt][0] + y2v);
      float d1 = fmaf(acc[1], -2.f * INV_LN2, x2q[MTB + mt][1] + y2v);
      float d2 = fmaf(acc[2], -2.f * INV_LN2, x2q[MTB + mt][2] + y2v);
      float d3 = fmaf(acc[3], -2.f * INV_LN2, x2q[MTB + mt][3] + y2v);
      unsigned p01 = cvt_pk_bf16(d0, d1);
      unsigned p23 = cvt_pk_bf16(d2, d3);
      const int cs = cb + nt * 16 + m + r0;          // col + local row (reg 0)
      ushort_t* base = Dtw + (rowBase + r0) * DSTR;
      base[             ((cs    ) & 127)] = (ushort_t)p01;
      base[    DSTR  +  ((cs + 1) & 127)] = (ushort_t)(p01 >> 16);
      base[2 * DSTR  +  ((cs + 2) & 127)] = (ushort_t)p23;
      base[3 * DSTR  +  ((cs + 3) & 127)] = (ushort_t)(p23 >> 16);
    }
  }
}

static __device__ __forceinline__ void spin_lds(int* f, int v) {
  int k = 0;
  while (__hip_atomic_load(f, __ATOMIC_ACQUIRE, __HIP_MEMORY_SCOPE_WORKGROUP) < v) {
    __builtin_amdgcn_s_sleep(1);
    if (++k > (1 << 26)) break;
  }
}
static __device__ __forceinline__ void spin_glb(int* f, int v) {
  int k = 0;
  while (__hip_atomic_load(f, __ATOMIC_ACQUIRE, __HIP_MEMORY_SCOPE_AGENT) < v) {
    __builtin_amdgcn_s_sleep(2);
    if (++k > (1 << 26)) break;
  }
}

// One 64-step chunk of the dual-band sweep.
// MODE: 0 = chunk0 (A start-gated, no B), 1 = chunk1 (A normal, B start-gated),
//       2 = steady, 3 = chunk16 (A end-gated, B normal), 4 = chunk17 (no A, B end-gated)
// HDST: 0 = bottom row -> LDS Hb, 1 = global HX, 2 = none (last band).
template<int HDST, int MODE>
static __device__ __forceinline__ void dp_chunk(
    const int t, const int lane,
    float& curA, float& curB, float& dgpA, float& dgpB,
    float hvv, const float zsel,
    const unsigned* __restrict__ pwA, const unsigned* __restrict__ pwB,
    float* __restrict__ HbDst, float* __restrict__ HXB)
{
  const int cb2 = (t << 6) - 127;   // lane-63 B col at step u is cb2+u
  unsigned aA0=0,aA1=0,aA2=0,aA3=0,aB0=0,aB1=0,aB2=0,aB3=0;
  if constexpr (MODE != 4) { aA0=pwA[0]; aA1=pwA[1]; aA2=pwA[2]; aA3=pwA[3]; }
  if constexpr (MODE != 0) { aB0=pwB[0]; aB1=pwB[1]; aB2=pwB[2]; aB3=pwB[3]; }

  auto step = [&](unsigned dwA, int kA, unsigned dwB, int kB, int u) -> float {
    float rolA = dpp_ror1(curA);          // lane0 <- lane63's A (prev step)
    float upA  = dpp_shr1(hvv, curA);     // lane0 <- external top value
    if constexpr (MODE != 4) {
      float dvA = __builtin_bit_cast(float, (kA & 1) ? (dwA & 0xffff0000u) : (dwA << 16));
      float dgA = dgpA, lfA = curA;
      if constexpr (MODE == 0) {
        const bool a0 = (u == lane);      // col == 0
        dgA = a0 ? zsel : dgA;
        lfA = a0 ? BIGV : lfA;
      }
      float mnA = fminf(fminf(upA, dgA), lfA);
      float eA = __builtin_amdgcn_exp2f(mnA - upA) + __builtin_amdgcn_exp2f(mnA - dgA)
               + __builtin_amdgcn_exp2f(mnA - lfA);
      float nvA = (dvA + mnA) - __builtin_amdgcn_logf(eA);
      if constexpr (MODE == 0)      { if (u >= lane) curA = nvA; }
      else if constexpr (MODE == 3) { if (u <  lane) curA = nvA; }
      else                          curA = nvA;
    }
    dgpA = upA;
    hvv = dpp_shl1(hvv);
    float nvB = 0.f;
    if constexpr (MODE != 0) {
      float upB = dpp_shr1(rolA, curB);   // lane0 <- A row63 (one step stale = exact)
      float dvB = __builtin_bit_cast(float, (kB & 1) ? (dwB & 0xffff0000u) : (dwB << 16));
      float dgB = dgpB, lfB = curB;
      if constexpr (MODE == 1) {
        const bool b0c = (u == lane);     // col == 0 (rows >= 64: diag is BIG)
        dgB = b0c ? BIGV : dgB;
        lfB = b0c ? BIGV : lfB;
      }
      float mnB = fminf(fminf(upB, dgB), lfB);
      float eB = __builtin_amdgcn_exp2f(mnB - upB) + __builtin_amdgcn_exp2f(mnB - dgB)
               + __builtin_amdgcn_exp2f(mnB - lfB);
      nvB = (dvB + mnB) - __builtin_amdgcn_logf(eB);
      dgpB = upB;
      if constexpr (MODE == 1) {
        if (u >= lane) {
          curB = nvB;
          if (lane == 63) {               // only u==63: bottom col 0
            if constexpr (HDST == 0) HbDst[0] = nvB;
            else if constexpr (HDST == 1) HXB[0] = nvB;
          }
        }
      } else if constexpr (MODE == 4) {
        if (u < lane) {
          curB = nvB;
          if (lane == 63) {               // bottom cols 961..1023
            if constexpr (HDST == 0) HbDst[961 + u] = nvB;
            else if constexpr (HDST == 1) HXB[961 + u] = nvB;
          }
        }
      } else {
        curB = nvB;
      }
    }
    return nvB;
  };

  #pragma unroll 1
  for (int g = 0; g < 8; ++g) {
    unsigned nA0=0,nA1=0,nA2=0,nA3=0,nB0=0,nB1=0,nB2=0,nB3=0;
    if (g < 7) {
      const int o = (g + 1) * 4;
      if constexpr (MODE != 4) { nA0=pwA[o]; nA1=pwA[o+1]; nA2=pwA[o+2]; nA3=pwA[o+3]; }
      if constexpr (MODE != 0) { nB0=pwB[o]; nB1=pwB[o+1]; nB2=pwB[o+2]; nB3=pwB[o+3]; }
    }
    const int u0 = g << 3;
    float v0 = step(aA0,0,aB0,0,u0+0);
    float v1 = step(aA0,1,aB0,1,u0+1);
    float v2 = step(aA1,0,aB1,0,u0+2);
    float v3 = step(aA1,1,aB1,1,u0+3);
    if constexpr (MODE == 2 || MODE == 3) {
      if (lane == 63) {
        if constexpr (HDST == 0) {
          HbDst[cb2+u0]=v0; HbDst[cb2+u0+1]=v1; HbDst[cb2+u0+2]=v2; HbDst[cb2+u0+3]=v3;
        } else if constexpr (HDST == 1) {
          HXB[cb2+u0]=v0; HXB[cb2+u0+1]=v1; HXB[cb2+u0+2]=v2; HXB[cb2+u0+3]=v3;
        }
      }
    }
    float v4 = step(aA2,0,aB2,0,u0+4);
    float v5 = step(aA2,1,aB2,1,u0+5);
    float v6 = step(aA3,0,aB3,0,u0+6);
    float v7 = step(aA3,1,aB3,1,u0+7);
    if constexpr (MODE == 2 || MODE == 3) {
      if (lane == 63) {
        if constexpr (HDST == 0) {
          HbDst[cb2+u0+4]=v4; HbDst[cb2+u0+5]=v5; HbDst[cb2+u0+6]=v6; HbDst[cb2+u0+7]=v7;
        } else if constexpr (HDST == 1) {
          HXB[cb2+u0+4]=v4; HXB[cb2+u0+5]=v5; HXB[cb2+u0+6]=v6; HXB[cb2+u0+7]=v7;
        }
      }
    }
    aA0=nA0; aA1=nA1; aA2=nA2; aA3=nA3;
    aB0=nB0; aB1=nB1; aB2=nB2; aB3=nB3;
    (void)v0;(void)v1;(void)v2;(void)v3;(void)v4;(void)v5;(void)v6;(void)v7;
  }
}

// HSRC: 0 = BIG top (band 0), 1 = LDS Hb, 2 = global HX.
// HDST: 0 = LDS Hb, 1 = global HX, 2 = none (band 7).
template<int HSRC, int HDST>
static __device__ __forceinline__ void run_band(
    const ushort_t* __restrict__ xbB, const ushort_t* __restrict__ ybB,
    const float* __restrict__ x2B, const float* __restrict__ y2B,
    const float* __restrict__ HXin, float* __restrict__ HXout,
    int* __restrict__ fGin, int* __restrict__ fGout,
    ushort_t* __restrict__ Dtw, const float* __restrict__ HbSrc,
    float* __restrict__ HbDst, int* __restrict__ cin, int* __restrict__ cout,
    const int lane, const int W, float* __restrict__ outp)
{
  const int m = lane & 15, q = lane >> 4;
  const int i0 = W * 128;

  short8 af[8][2];
  #pragma unroll
  for (int mt = 0; mt < 8; ++mt)
    #pragma unroll
    for (int ks = 0; ks < 2; ++ks)
      af[mt][ks] = *(const short8*)(xbB + (size_t)(i0 + mt * 16 + m) * C_ + ks * 32 + q * 8);
  f32x4 x2q[8];
  #pragma unroll
  for (int mt = 0; mt < 8; ++mt) x2q[mt] = *(const f32x4*)(x2B + i0 + mt * 16 + q * 4);

  short8 bc0[4], bc1[4], bn0[4], bn1[4];
  f32x4 y2c = {0.f,0.f,0.f,0.f}, y2n = {0.f,0.f,0.f,0.f};
  auto load_y = [&](int tc, short8 (&b0)[4], short8 (&b1)[4], f32x4& y2r) {
    const ushort_t* yb0 = ybB + (size_t)tc * 64 * C_;
    #pragma unroll
    for (int nt = 0; nt < 4; ++nt) {
      b0[nt] = *(const short8*)(yb0 + (size_t)(nt * 16 + m) * C_ + q * 8);
      b1[nt] = *(const short8*)(yb0 + (size_t)(nt * 16 + m) * C_ + 32 + q * 8);
    }
    const float* y2j = y2B + tc * 64;
    #pragma unroll
    for (int nt = 0; nt < 4; ++nt) y2r[nt] = y2j[nt * 16 + m];
  };
  auto rot = [&]() {
    #pragma unroll
    for (int nt = 0; nt < 4; ++nt) { bc0[nt] = bn0[nt]; bc1[nt] = bn1[nt]; }
    y2c = y2n;
  };
  auto get_hvv = [&](int t) -> float {
    if constexpr (HSRC == 0) return BIGV;
    else if constexpr (HSRC == 1) { spin_lds(cin, t + 1); return HbSrc[(t << 6) + lane]; }
    else { spin_glb(fGin, t + 1); return HXin[(t << 6) + lane]; }
  };
  auto signal = [&](int v) {
    if constexpr (HDST == 0) {
      if (lane == 0) __hip_atomic_store(cout, v, __ATOMIC_RELEASE, __HIP_MEMORY_SCOPE_WORKGROUP);
    } else if constexpr (HDST == 1) {
      if (lane == 0) __hip_atomic_store(fGout, v, __ATOMIC_RELEASE, __HIP_MEMORY_SCOPE_AGENT);
    }
  };

  float curA = 0.f, curB = 0.f, dgpA = BIGV, dgpB = BIGV;
  const float zsel = (W == 0 && lane == 0) ? 0.f : BIGV;
  const unsigned* DtU = (const unsigned*)Dtw;
  const unsigned* pA = DtU + lane * (DSTR / 2);
  const unsigned* pB = DtU + (64 + lane) * (DSTR / 2);

  load_y(0, bc0, bc1, y2c);
  gram_tile<0>(af, x2q, bc0, bc1, y2c, Dtw, 0, 0, m, q);

  // t = 0: A start-gated, no B
  load_y(1, bn0, bn1, y2n);
  { float hv = get_hvv(0);
    dp_chunk<HDST, 0>(0, lane, curA, curB, dgpA, dgpB, hv, zsel, pA, pB, HbDst, HXout); }
  gram_tile<0>(af, x2q, bn0, bn1, y2n, Dtw, 0, 64, m, q);     // A tile 1
  gram_tile<4>(af, x2q, bc0, bc1, y2c, Dtw, 64, 0, m, q);     // B tile 0
  rot();

  // t = 1: A normal, B start-gated
  load_y(2, bn0, bn1, y2n);
  { float hv = get_hvv(1);
    dp_chunk<HDST, 1>(1, lane, curA, curB, dgpA, dgpB, hv, zsel, pA + 32, pB, HbDst, HXout); }
  gram_tile<0>(af, x2q, bn0, bn1, y2n, Dtw, 0, 128, m, q);    // A tile 2
  gram_tile<4>(af, x2q, bc0, bc1, y2c, Dtw, 64, 64, m, q);    // B tile 1
  rot();

  // t = 2..14: steady
  #pragma unroll 1
  for (int t = 2; t <= 14; ++t) {
    load_y(t + 1, bn0, bn1, y2n);
    float hv = get_hvv(t);
    dp_chunk<HDST, 2>(t, lane, curA, curB, dgpA, dgpB, hv, zsel,
                      pA + ((t & 1) << 5), pB + (((t & 1) ^ 1) << 5), HbDst, HXout);
    signal(t - 1);
    gram_tile<0>(af, x2q, bn0, bn1, y2n, Dtw, 0, (t + 1) << 6, m, q);
    gram_tile<4>(af, x2q, bc0, bc1, y2c, Dtw, 64, t << 6, m, q);
    rot();
  }

  // t = 15: steady (no A prefetch beyond tile 15)
  { float hv = get_hvv(15);
    dp_chunk<HDST, 2>(15, lane, curA, curB, dgpA, dgpB, hv, zsel, pA + 32, pB, HbDst, HXout);
    signal(14);
    gram_tile<4>(af, x2q, bc0, bc1, y2c, Dtw, 64, 15 << 6, m, q); }

  // t = 16: A end-gated (no top consumption), B normal
  dp_chunk<HDST, 3>(16, lane, curA, curB, dgpA, dgpB, BIGV, zsel, pA, pB + 32, HbDst, HXout);
  signal(15);

  // t = 17: B end-gated only
  dp_chunk<HDST, 4>(17, lane, curA, curB, dgpA, dgpB, BIGV, zsel, pA + 32, pB, HbDst, HXout);
  signal(16);

  if (W == 7 && lane == 63) *outp = curB * LN2F;
}

__global__ __launch_bounds__(256) void sdtw_kernel(
    const ushort_t* __restrict__ xb, const ushort_t* __restrict__ yb,
    const float* __restrict__ x2g, const float* __restrict__ y2g,
    float* __restrict__ HXg, int* __restrict__ flagsG,
    float* __restrict__ out)
{
  // LDS: Dt 4*128*130*2 = 133120 ; Hb 3*1024*4 = 12288 ; cflag 16 => 145424 B
  __shared__ ushort_t Dt[4][128 * DSTR];
  __shared__ float Hb[3][1024];
  __shared__ int cflag[4];

  const int b = blockIdx.x & 63;      // blocks b and b+64 land on the same XCD slot
  const int half = blockIdx.x >> 6;   // 0: bands 0-3, 1: bands 4-7
  const int w = threadIdx.x >> 6;
  const int lane = threadIdx.x & 63;
  const int W = half * 4 + w;

  if (threadIdx.x < 4) cflag[threadIdx.x] = 0;
  __syncthreads();                    // only barrier in the kernel

  const ushort_t* xbB = xb + (size_t)b * L_ * C_;
  const ushort_t* ybB = yb + (size_t)b * L_ * C_;
  const float* x2B = x2g + b * L_;
  const float* y2B = y2g + b * L_;
  const float* HXin = HXg + (size_t)b * L_;
  float* HXout     = HXg + (size_t)b * L_;
  int* fGin  = flagsG + b;
  int* fGout = flagsG + b;
  ushort_t* Dtw = &Dt[w][0];
  const float* HbSrc = (w > 0) ? &Hb[w - 1][0] : &Hb[0][0];
  float* HbDst = (w < 3) ? &Hb[w][0] : &Hb[0][0];
  int* cin  = (w > 0) ? &cflag[w - 1] : &cflag[0];
  int* cout = (w < 3) ? &cflag[w] : &cflag[3];
  float* outp = out + b;

  if (half == 0) {
    if (w == 0)
      run_band<0, 0>(xbB, ybB, x2B, y2B, HXin, HXout, fGin, fGout, Dtw, HbSrc, HbDst, cin, cout, lane, W, outp);
    else if (w < 3)
      run_band<1, 0>(xbB, ybB, x2B, y2B, HXin, HXout, fGin, fGout, Dtw, HbSrc, HbDst, cin, cout, lane, W, outp);
    else
      run_band<1, 1>(xbB, ybB, x2B, y2B, HXin, HXout, fGin, fGout, Dtw, HbSrc, HbDst, cin, cout, lane, W, outp);
  } else {
    if (w == 0)
      run_band<2, 0>(xbB, ybB, x2B, y2B, HXin, HXout, fGin, fGout, Dtw, HbSrc, HbDst, cin, cout, lane, W, outp);
    else if (w < 3)
      run_band<1, 0>(xbB, ybB, x2B, y2B, HXin, HXout, fGin, fGout, Dtw, HbSrc, HbDst, cin, cout, lane, W, outp);
    else
      run_band<1, 2>(xbB, ybB, x2B, y2B, HXin, HXout, fGin, fGout, Dtw, HbSrc, HbDst, cin, cout, lane, W, outp);
  }
}

extern "C" void kernel_launch(void* const* d_in, const int* in_sizes, int n_in,
                              void* d_out, int out_size, void* d_ws, size_t ws_size,
                              hipStream_t stream) {
  const float* x = (const float*)d_in[0];
  const float* y = (const float*)d_in[1];
  float* out = (float*)d_out;

  // ws: xb 8MB | yb 8MB | x2 256KB | y2 256KB | HX 256KB | flagsG 256B
  char* ws = (char*)d_ws;
  const size_t XB = (size_t)B_ * L_ * C_ * 2;
  const size_t NB = (size_t)B_ * L_ * 4;
  ushort_t* xb = (ushort_t*)ws;
  ushort_t* yb = (ushort_t*)(ws + XB);
  float* x2 = (float*)(ws + 2 * XB);
  float* y2 = (float*)(ws + 2 * XB + NB);
  float* HX = (float*)(ws + 2 * XB + 2 * NB);
  int* flagsG = (int*)(ws + 2 * XB + 3 * NB);

  prep_kernel<<<512, 256, 0, stream>>>(x, y, xb, yb, x2, y2, flagsG);
  sdtw_kernel<<<128, 256, 0, stream>>>(xb, yb, x2, y2, HX, flagsG, out);
}